// Round 1
// 406.076 us; speedup vs baseline: 1.0246x; 1.0246x over previous
//
#include <hip/hip_runtime.h>

// BasalGanglia fused kernel (MI355X / gfx950).
// R7: occupancy + barrier restructure.
// Theory: R6 was latency/barrier-bound: 94KB LDS -> 1 block/CU, 8 waves/CU = 23%
// occupancy, 4 barriers x 50 iters; MfmaUtil 15%, VALUBusy 29%, HBM 0.4% -> ~8k
// stall cycles per 15.2k-cycle iteration.
// Changes vs R6:
//  - 768 threads (12 waves, BM=32 kept): 3 waves/SIMD latency hiding. 21 A-tile
//    slots spread over 12 waves -> per-wave A-frag regs 120->80 (fits 170-reg cap).
//  - 4 -> 3 barriers/iter: b4 removed (LSTM->next-PhaseA is hazard-free; gates/hxf
//    WAR ordered by b1/b2 of next iter); hh-gate MFMAs moved to Phase B (waves
//    7-11); stngpi split over waves 9/10/11 with LDS partial sums; vgpi state
//    register-replicated per LSTM thread (kills divergent wave5-q0 section).
//  - LSTM tail removed: 640 elems <= 768 threads, one elem/thread.
//  - s_setprio(1) around Phase-A MFMA cluster (T5).

typedef _Float16 f16_t;
typedef _Float16 f16x8 __attribute__((ext_vector_type(8)));
typedef _Float16 f16x4 __attribute__((ext_vector_type(4)));
typedef float floatx4 __attribute__((ext_vector_type(4)));
typedef float floatx2 __attribute__((ext_vector_type(2)));

#define BTOT 8192
#define BM   32
#define NTHR 768
#define NBLK 256
#define VSTR 328   // f16 stride; dword-stride 164 -> uniform 8-lane bank groups
#define XST  32    // xgpe/hxf row stride (f16), k-pad zeroed

struct Params {
  const float *stimulus, *deltavf, *hx0, *cx0;
  const float *w_vf0, *b_vf0, *w_vf1, *b_vf1, *w_vf2, *b_vf2, *w_vf3, *b_vf3;
  const float *w_jd1, *b_jd1, *w_jd2, *b_jd2, *w_kd1, *b_kd1, *w_kd2, *b_kd2;
  const float *w_sg, *b_sg, *w_gs, *b_gs, *w_glat, *b_glat, *w_slat, *b_slat;
  const float *w_d1gpi, *b_d1gpi, *w_stngpi, *b_stngpi;
  const float *w_ih, *b_ih, *w_hh, *b_hh;
  float* out;
};

struct __align__(16) Smem {
  f16_t vstn[BM * VSTR];        // 20992 B
  f16_t xgpe[2][BM * XST];      // 4096 (double buffer)
  f16_t hxf[BM * XST];          // 2048
  f16_t wB2[21 * 512];          // 21504: t<19 gs-frag, t=19/20 glat-frag
  f16_t wsp[10 * 512];          // 10240: stngpi frags
  f16_t whh[5 * 512];           // 5120: w_hh gate frags
  union { float h1f[BM * 128]; float scr[3200]; float gates[BM * 80]; } u; // 16384
  float h0f[BM * 64];           // 8192
  float V_D2f[BM * 20];         // 2560
  float pp[3][64];              // 768: stngpi partial sums (waves 9/10/11)
  float bsumS[304];             // b_slat+b_gs, pad->0
  float bsg[20];                // b_sg+b_glat
  float bihh[80], wih0[80], wih1[80];
  float DPs[BM * 2], lamS[BM];
};                              // ~94.5 KB -> 1 block/CU

__device__ __forceinline__ float rcp_f(float x) { return __builtin_amdgcn_rcpf(x); }
__device__ __forceinline__ float sigm_fast(float x) { return rcp_f(1.f + __expf(-x)); }
__device__ __forceinline__ float tanh_fast(float x) { return 1.f - 2.f * rcp_f(1.f + __expf(2.f * x)); }

// 8 f32 weights row[k0..k0+7] -> f16x8, zero for k>=kmax or !valid (4-granular).
__device__ __forceinline__ f16x8 ldfrag(const float* row, int k0, int kmax, bool valid) {
  float4 z = make_float4(0.f, 0.f, 0.f, 0.f);
  int nv = valid ? (kmax - k0) : 0;
  float4 f0 = (nv >= 4) ? *(const float4*)(row + k0) : z;
  float4 f1 = (nv >= 8) ? *(const float4*)(row + k0 + 4) : z;
  f16x8 r;
  r[0] = (f16_t)f0.x; r[1] = (f16_t)f0.y; r[2] = (f16_t)f0.z; r[3] = (f16_t)f0.w;
  r[4] = (f16_t)f1.x; r[5] = (f16_t)f1.y; r[6] = (f16_t)f1.z; r[7] = (f16_t)f1.w;
  return r;
}

__global__ __launch_bounds__(NTHR, 3) void bg_main(Params P) {
  __shared__ Smem S;
  const int tid  = threadIdx.x;
  const int lane = tid & 63;
  const int wv   = tid >> 6;          // 0..11
  const int q    = lane >> 4;
  const int cl   = lane & 15;
  const int row0 = blockIdx.x * BM;
  const floatx4 zf = {0.f, 0.f, 0.f, 0.f};

  // ---- tile-slot map (21 slots over 12 waves; SIMD pairs wv%4) ----
  // j0: slat tile t = wv (0..11).  j1: wv0-6 -> slat 12..18; wv7 -> sg0(t19);
  // wv8 -> sg1(t20); wv9-11 none.  Gate tiles: wv7..11 -> g3,g4,g0,g1,g2.
  // stngpi partials: wv9 c0-3, wv10 c4-6, wv11 c7-9.
  const int  t0s  = wv;
  const int  t1s  = (wv < 7) ? (12 + wv) : (wv == 7 ? 19 : (wv == 8 ? 20 : 255));
  const bool has1 = (t1s != 255);
  const bool isSg = (t1s == 19 || t1s == 20);
  const bool gs1  = (t1s < 19);
  const int  gtile = (wv >= 9) ? (wv - 9) : (wv == 7 ? 3 : (wv == 8 ? 4 : -1));

  // ================= init + LDS weight-frag staging =================
  if (tid < BM) S.lamS[tid] = sigm_fast(P.deltavf[row0 + tid]);
  for (int i = tid; i < 2 * BM * XST; i += NTHR) ((f16_t*)S.xgpe)[i] = (f16_t)0.f;
  for (int i = tid; i < BM * XST; i += NTHR) {
    int m = i >> 5, j = i & 31;
    S.hxf[i] = (j < 20) ? (f16_t)P.hx0[row0 * 20 + m * 20 + j] : (f16_t)0.f;
  }
  for (int i = tid; i < BM * VSTR; i += NTHR) S.vstn[i] = (f16_t)0.f;
  for (int i = tid; i < 21 * 512; i += NTHR) {        // gs / glat frags
    int t = i >> 9, l = (i >> 3) & 63, jj = i & 7;
    int c2 = l & 15, k = ((l >> 4) << 3) + jj;
    float v = 0.f;
    if (t < 19) { int n = t * 16 + c2; if (n < 300 && k < 20) v = P.w_gs[n * 20 + k]; }
    else        { int g = (t - 19) * 16 + c2; if (g < 20 && k < 20) v = P.w_glat[g * 20 + k]; }
    S.wB2[i] = (f16_t)v;
  }
  for (int i = tid; i < 10 * 512; i += NTHR) {        // stngpi frags
    int c = i >> 9, l = (i >> 3) & 63, jj = i & 7;
    int p = l & 15, k = c * 32 + ((l >> 4) << 3) + jj;
    float v = (p < 2 && k < 300) ? P.w_stngpi[p * 300 + k] : 0.f;
    S.wsp[i] = (f16_t)v;
  }
  for (int i = tid; i < 5 * 512; i += NTHR) {         // w_hh gate frags
    int t = i >> 9, l = (i >> 3) & 63, jj = i & 7;
    int g = t * 16 + (l & 15), k = ((l >> 4) << 3) + jj;
    S.whh[i] = (f16_t)((k < 20) ? P.w_hh[g * 20 + k] : 0.f);
  }
  for (int i = tid; i < 304; i += NTHR) S.bsumS[i] = (i < 300) ? (P.b_slat[i] + P.b_gs[i]) : 0.f;
  for (int i = tid; i < 20; i += NTHR)  S.bsg[i] = P.b_sg[i] + P.b_glat[i];
  for (int i = tid; i < 80; i += NTHR) {
    S.bihh[i] = P.b_ih[i] + P.b_hh[i];
    S.wih0[i] = P.w_ih[i * 2 + 0];
    S.wih1[i] = P.w_ih[i * 2 + 1];
  }

  if (tid < 512) { // h0 = relu(stim @ w_vf0^T + b)
    int o = tid & 63, mb = (tid >> 6) * 4;
    const float4* wr = (const float4*)(P.w_vf0 + o * 300);
    float bias = P.b_vf0[o], a[4];
#pragma unroll
    for (int u = 0; u < 4; ++u) a[u] = bias;
    for (int kq = 0; kq < 75; ++kq) {
      float4 w = wr[kq];
#pragma unroll
      for (int u = 0; u < 4; ++u) {
        float4 v = *(const float4*)(P.stimulus + (size_t)(row0 + mb + u) * 300 + kq * 4);
        a[u] = fmaf(v.x, w.x, a[u]); a[u] = fmaf(v.y, w.y, a[u]);
        a[u] = fmaf(v.z, w.z, a[u]); a[u] = fmaf(v.w, w.w, a[u]);
      }
    }
#pragma unroll
    for (int u = 0; u < 4; ++u) S.h0f[(mb + u) * 64 + o] = fmaxf(a[u], 0.f);
  }
  __syncthreads();
  if (tid < 512) { // h1
    int o = tid & 127, mb = (tid >> 7) * 8;
    const float* wr = P.w_vf1 + o * 64;
    float bias = P.b_vf1[o], a[8];
#pragma unroll
    for (int u = 0; u < 8; ++u) a[u] = bias;
    for (int k = 0; k < 64; ++k) {
      float w = wr[k];
#pragma unroll
      for (int u = 0; u < 8; ++u) a[u] = fmaf(S.h0f[(mb + u) * 64 + k], w, a[u]);
    }
#pragma unroll
    for (int u = 0; u < 8; ++u) S.u.h1f[(mb + u) * 128 + o] = fmaxf(a[u], 0.f);
  }
  __syncthreads();
  if (tid < 512) { // h2 -> h0f
    int o = tid & 63, mb = (tid >> 6) * 4;
    const float* wr = P.w_vf2 + o * 128;
    float bias = P.b_vf2[o], a[4];
#pragma unroll
    for (int u = 0; u < 4; ++u) a[u] = bias;
    for (int k = 0; k < 128; ++k) {
      float w = wr[k];
#pragma unroll
      for (int u = 0; u < 4; ++u) a[u] = fmaf(S.u.h1f[(mb + u) * 128 + k], w, a[u]);
    }
#pragma unroll
    for (int u = 0; u < 4; ++u) S.h0f[(mb + u) * 64 + o] = fmaxf(a[u], 0.f);
  }
  __syncthreads();
  { // drives -> scr[0:2560); vt output
    int oid = tid & 127, mb = (tid >> 7) * 8;
    if (tid < 512 && oid < 80) {
      int which = oid / 20, o = oid - which * 20;
      const float *wp, *bp;
      if (which == 0)      { wp = P.w_jd1; bp = P.b_jd1; }
      else if (which == 1) { wp = P.w_jd2; bp = P.b_jd2; }
      else if (which == 2) { wp = P.w_kd1; bp = P.b_kd1; }
      else                 { wp = P.w_kd2; bp = P.b_kd2; }
      float bias = bp[o], a[8];
#pragma unroll
      for (int u = 0; u < 8; ++u) a[u] = bias;
      for (int kq = 0; kq < 75; ++kq) {
        float4 w = *(const float4*)(wp + o * 300 + kq * 4);
#pragma unroll
        for (int u = 0; u < 8; ++u) {
          float4 v = *(const float4*)(P.stimulus + (size_t)(row0 + mb + u) * 300 + kq * 4);
          a[u] = fmaf(v.x, w.x, a[u]); a[u] = fmaf(v.y, w.y, a[u]);
          a[u] = fmaf(v.z, w.z, a[u]); a[u] = fmaf(v.w, w.w, a[u]);
        }
      }
#pragma unroll
      for (int u = 0; u < 8; ++u) S.u.scr[which * 640 + (mb + u) * 20 + o] = a[u];
    }
    if (tid < BM) {
      float a = P.b_vf3[0];
      for (int k = 0; k < 64; ++k) a = fmaf(S.h0f[tid * 64 + k], P.w_vf3[k], a);
      P.out[(size_t)BTOT * 20 + row0 + tid] = tanh_fast(a);
    }
  }
  __syncthreads();
  for (int i = tid; i < BM * 20; i += NTHR) { // FF -> V_D1 scr[2560:), V_D2f
    int m = i / 20;
    float j1 = S.u.scr[i],        j2 = S.u.scr[640 + i];
    float k1 = S.u.scr[1280 + i], k2 = S.u.scr[1920 + i];
    float L = S.lamS[m], v1 = 0.f, v2 = 0.f;
    for (int s = 0; s < 20; ++s) {
      v1 = sigm_fast(L * (j1 * (1.f - v1) + (1.f - k1) * v1));
      v2 = sigm_fast(L * (j2 * (1.f - v2) + (1.f - k2) * v2));
    }
    S.u.scr[2560 + i] = v1;
    S.V_D2f[i] = v2;
  }
  __syncthreads();
  if (tid < BM * 2) { // V_GPi_DP
    int m = tid >> 1, p2 = tid & 1;
    float a = P.b_d1gpi[p2];
    for (int o = 0; o < 20; ++o) a = fmaf(S.u.scr[2560 + m * 20 + o], P.w_d1gpi[p2 * 20 + o], a);
    S.DPs[tid] = a;
  }
  __syncthreads();

  // ================= per-thread loop-invariant state =================
  const float lam0 = S.lamS[cl], lam1 = S.lamS[cl + 16];
  const float bstn0 = P.b_stngpi[0], bstn1 = P.b_stngpi[1];
  const bool lown = (tid < BM * 20);            // 640 LSTM threads, 1 elem each
  const int  m0 = lown ? tid / 20 : 0;
  const int  j0 = tid - m0 * 20;
  const float lamr = S.lamS[m0];
  const float DP0 = S.DPs[m0 * 2], DP1 = S.DPs[m0 * 2 + 1];
  float cxr0 = lown ? P.cx0[row0 * 20 + tid] : 0.f;
  float hxr0 = 0.f;
  float vg0 = 0.f, vg1 = 0.f;                   // vgpi replicated in registers

  // ---- register-resident A-frags (slat / sg), 2 slots/wave ----
  f16x8 Ws[2][10];
  {
    int n = t0s * 16 + cl;                      // t0s<=11 -> always valid
    const float* a0 = P.w_slat + (size_t)n * 300;
#pragma unroll
    for (int c = 0; c < 10; ++c) Ws[0][c] = ldfrag(a0, c * 32 + q * 8, 300, true);
    if (t1s < 19) {
      int n1 = t1s * 16 + cl;
      const float* a1 = P.w_slat + (size_t)(n1 < 300 ? n1 : 0) * 300;
#pragma unroll
      for (int c = 0; c < 10; ++c) Ws[1][c] = ldfrag(a1, c * 32 + q * 8, 300, n1 < 300);
    } else if (isSg) {
      int g = (t1s - 19) * 16 + cl;
      const float* a1 = P.w_sg + (size_t)(g < 20 ? g : 0) * 300;
#pragma unroll
      for (int c = 0; c < 10; ++c) Ws[1][c] = ldfrag(a1, c * 32 + q * 8, 300, g < 20);
    } else {
      f16x8 z;
#pragma unroll
      for (int e = 0; e < 8; ++e) z[e] = (f16_t)0.f;
#pragma unroll
      for (int c = 0; c < 10; ++c) Ws[1][c] = z;
    }
  }

  float xs[2][2][4];
#pragma unroll
  for (int j = 0; j < 2; ++j)
#pragma unroll
    for (int mf = 0; mf < 2; ++mf)
#pragma unroll
      for (int r = 0; r < 4; ++r) xs[j][mf][r] = 0.f;

  // ================= STN recurrence, 50 iterations, 3 barriers/iter =========
  for (int it = 0; it < 50; ++it) {
    const int po = it & 1, pn = po ^ 1;
    floatx4 acc[2][2];
    acc[0][0] = zf; acc[0][1] = zf; acc[1][0] = zf; acc[1][1] = zf;

    // ---- Phase A: [slat|sg] @ vstn^T (+ glat @ xgpe_old^T); xgpe_new pack ----
    __builtin_amdgcn_s_setprio(1);
    if (has1) {
#pragma unroll
      for (int c = 0; c < 10; ++c) {
        f16x8 b0 = *(const f16x8*)&S.vstn[cl * VSTR + c * 32 + q * 8];
        f16x8 b1 = *(const f16x8*)&S.vstn[(16 + cl) * VSTR + c * 32 + q * 8];
        acc[0][0] = __builtin_amdgcn_mfma_f32_16x16x32_f16(Ws[0][c], b0, acc[0][0], 0, 0, 0);
        acc[0][1] = __builtin_amdgcn_mfma_f32_16x16x32_f16(Ws[0][c], b1, acc[0][1], 0, 0, 0);
        acc[1][0] = __builtin_amdgcn_mfma_f32_16x16x32_f16(Ws[1][c], b0, acc[1][0], 0, 0, 0);
        acc[1][1] = __builtin_amdgcn_mfma_f32_16x16x32_f16(Ws[1][c], b1, acc[1][1], 0, 0, 0);
      }
    } else {
#pragma unroll
      for (int c = 0; c < 10; ++c) {
        f16x8 b0 = *(const f16x8*)&S.vstn[cl * VSTR + c * 32 + q * 8];
        f16x8 b1 = *(const f16x8*)&S.vstn[(16 + cl) * VSTR + c * 32 + q * 8];
        acc[0][0] = __builtin_amdgcn_mfma_f32_16x16x32_f16(Ws[0][c], b0, acc[0][0], 0, 0, 0);
        acc[0][1] = __builtin_amdgcn_mfma_f32_16x16x32_f16(Ws[0][c], b1, acc[0][1], 0, 0, 0);
      }
    }
    __builtin_amdgcn_s_setprio(0);
    if (isSg) {
      f16x8 Wg = *(const f16x8*)&S.wB2[t1s * 512 + lane * 8];
      f16x8 g0 = *(const f16x8*)&S.xgpe[po][cl * XST + q * 8];
      f16x8 g1 = *(const f16x8*)&S.xgpe[po][(16 + cl) * XST + q * 8];
      acc[1][0] = __builtin_amdgcn_mfma_f32_16x16x32_f16(Wg, g0, acc[1][0], 0, 0, 0);
      acc[1][1] = __builtin_amdgcn_mfma_f32_16x16x32_f16(Wg, g1, acc[1][1], 0, 0, 0);
      int g0i = (t1s - 19) * 16 + q * 4;
      if (g0i < 20) {
        floatx4 bg4 = *(const floatx4*)&S.bsg[g0i];
#pragma unroll
        for (int mf = 0; mf < 2; ++mf) {
          int batch = cl + 16 * mf;
          floatx4 vd4 = *(const floatx4*)&S.V_D2f[batch * 20 + g0i];
          f16x4 pk;
#pragma unroll
          for (int r = 0; r < 4; ++r) pk[r] = (f16_t)(acc[1][mf][r] + bg4[r] - vd4[r]);
          *(f16x4*)&S.xgpe[pn][batch * XST + g0i] = pk;
        }
      }
    }
    __syncthreads(); // b1: xgpe_new ready

    // ---- Phase B: acc += gs @ xgpe_new^T; hh-gate MFMAs; xstn/vstn update ----
    {
      f16x8 x0 = *(const f16x8*)&S.xgpe[pn][cl * XST + q * 8];
      f16x8 x1 = *(const f16x8*)&S.xgpe[pn][(16 + cl) * XST + q * 8];
      {
        f16x8 Wg0 = *(const f16x8*)&S.wB2[t0s * 512 + lane * 8];
        acc[0][0] = __builtin_amdgcn_mfma_f32_16x16x32_f16(Wg0, x0, acc[0][0], 0, 0, 0);
        acc[0][1] = __builtin_amdgcn_mfma_f32_16x16x32_f16(Wg0, x1, acc[0][1], 0, 0, 0);
      }
      if (gs1) {
        f16x8 Wg1 = *(const f16x8*)&S.wB2[t1s * 512 + lane * 8];
        acc[1][0] = __builtin_amdgcn_mfma_f32_16x16x32_f16(Wg1, x0, acc[1][0], 0, 0, 0);
        acc[1][1] = __builtin_amdgcn_mfma_f32_16x16x32_f16(Wg1, x1, acc[1][1], 0, 0, 0);
      }
      if (gtile >= 0) { // hh-gates for this iter's LSTM (hxf stable since b1)
        f16x8 Wh = *(const f16x8*)&S.whh[gtile * 512 + lane * 8];
        f16x8 h0 = *(const f16x8*)&S.hxf[cl * XST + q * 8];
        f16x8 h1 = *(const f16x8*)&S.hxf[(16 + cl) * XST + q * 8];
        floatx4 gA = __builtin_amdgcn_mfma_f32_16x16x32_f16(Wh, h0, zf, 0, 0, 0);
        floatx4 gB = __builtin_amdgcn_mfma_f32_16x16x32_f16(Wh, h1, zf, 0, 0, 0);
        int gb = gtile * 16 + q * 4;
        *(floatx4*)&S.u.gates[cl * 80 + gb] = gA;
        *(floatx4*)&S.u.gates[(cl + 16) * 80 + gb] = gB;
      }
      // xstn update + vstn pack for valid slat/gs slots
#pragma unroll
      for (int j = 0; j < 2; ++j) {
        int t = j ? t1s : t0s;
        if (t < 19) {
          int n0 = t * 16 + q * 4;
          if (!(t == 18 && q == 3)) {  // n0..n0+3 all < 300
            floatx4 bs4 = *(const floatx4*)&S.bsumS[n0];
#pragma unroll
            for (int mf = 0; mf < 2; ++mf) {
              float lm = mf ? lam1 : lam0;
              f16x4 pk;
#pragma unroll
              for (int r = 0; r < 4; ++r) {
                float xo = xs[j][mf][r];
                float xn = xo + (1.0f / 3.0f) * (acc[j][mf][r] + bs4[r] - xo);
                xs[j][mf][r] = xn;
                pk[r] = (f16_t)tanh_fast(lm * xn);
              }
              *(f16x4*)&S.vstn[(cl + 16 * mf) * VSTR + n0] = pk;
            }
          }
        }
      }
    }
    __syncthreads(); // b2: vstn_new + gates ready

    // ---- Phase C: stngpi partials on waves 9/10/11 ----
    if (wv >= 9) {
      const int c0 = (wv == 9) ? 0 : (wv == 10 ? 4 : 7);
      const int c1 = (wv == 9) ? 4 : (wv == 10 ? 7 : 10);
      floatx4 ip0 = zf, ip1 = zf;
      for (int c = c0; c < c1; ++c) {
        f16x8 Wp = *(const f16x8*)&S.wsp[c * 512 + lane * 8];
        f16x8 b0 = *(const f16x8*)&S.vstn[cl * VSTR + c * 32 + q * 8];
        f16x8 b1 = *(const f16x8*)&S.vstn[(16 + cl) * VSTR + c * 32 + q * 8];
        ip0 = __builtin_amdgcn_mfma_f32_16x16x32_f16(Wp, b0, ip0, 0, 0, 0);
        ip1 = __builtin_amdgcn_mfma_f32_16x16x32_f16(Wp, b1, ip1, 0, 0, 0);
      }
      if (q == 0) { // rows p=0,1 live in regs 0,1 of the q==0 lanes
        floatx2 w0; w0[0] = ip0[0]; w0[1] = ip0[1];
        floatx2 w1; w1[0] = ip1[0]; w1[1] = ip1[1];
        *(floatx2*)&S.pp[wv - 9][cl * 2] = w0;
        *(floatx2*)&S.pp[wv - 9][(16 + cl) * 2] = w1;
      }
    }
    __syncthreads(); // b3: partials ready

    // ---- LSTM pointwise: vgpi update (register-replicated) + cell ----
    if (lown) {
      float s0 = S.pp[0][m0 * 2]     + S.pp[1][m0 * 2]     + S.pp[2][m0 * 2];
      float s1 = S.pp[0][m0 * 2 + 1] + S.pp[1][m0 * 2 + 1] + S.pp[2][m0 * 2 + 1];
      float ipa = lamr * (s0 + bstn0);
      float ipb = lamr * (s1 + bstn1);
      vg0 = vg0 + 0.1f * (-vg0 - DP0 + 2.f * ipa);
      vg1 = vg1 + 0.1f * (-vg1 - DP1 + 2.f * ipb);
      float gi = S.u.gates[m0 * 80 + j0]      + S.bihh[j0]      - S.wih0[j0] * vg0      - S.wih1[j0] * vg1;
      float gf = S.u.gates[m0 * 80 + 20 + j0] + S.bihh[20 + j0] - S.wih0[20 + j0] * vg0 - S.wih1[20 + j0] * vg1;
      float gg = S.u.gates[m0 * 80 + 40 + j0] + S.bihh[40 + j0] - S.wih0[40 + j0] * vg0 - S.wih1[40 + j0] * vg1;
      float go = S.u.gates[m0 * 80 + 60 + j0] + S.bihh[60 + j0] - S.wih0[60 + j0] * vg0 - S.wih1[60 + j0] * vg1;
      float cn = sigm_fast(gf) * cxr0 + sigm_fast(gi) * tanh_fast(gg);
      cxr0 = cn;
      hxr0 = sigm_fast(go) * tanh_fast(cn);
      S.hxf[m0 * XST + j0] = (f16_t)hxr0;
    }
    // no barrier: next Phase A touches only vstn/xgpe/Ws (ordered by b1/b2/b3);
    // hxf/gates WAR vs next Phase B is ordered by next iter's b1.
  }

  // ---- output hx from registers ----
  if (lown) P.out[(size_t)row0 * 20 + tid] = hxr0;
}

extern "C" void kernel_launch(void* const* d_in, const int* in_sizes, int n_in,
                              void* d_out, int out_size, void* d_ws, size_t ws_size,
                              hipStream_t stream) {
  (void)in_sizes; (void)n_in; (void)out_size; (void)d_ws; (void)ws_size;
  Params P;
  P.stimulus = (const float*)d_in[0];
  P.deltavf  = (const float*)d_in[1];
  P.hx0 = (const float*)d_in[2];
  P.cx0 = (const float*)d_in[3];
  P.w_vf0 = (const float*)d_in[4];  P.b_vf0 = (const float*)d_in[5];
  P.w_vf1 = (const float*)d_in[6];  P.b_vf1 = (const float*)d_in[7];
  P.w_vf2 = (const float*)d_in[8];  P.b_vf2 = (const float*)d_in[9];
  P.w_vf3 = (const float*)d_in[10]; P.b_vf3 = (const float*)d_in[11];
  P.w_jd1 = (const float*)d_in[12]; P.b_jd1 = (const float*)d_in[13];
  P.w_jd2 = (const float*)d_in[14]; P.b_jd2 = (const float*)d_in[15];
  P.w_kd1 = (const float*)d_in[16]; P.b_kd1 = (const float*)d_in[17];
  P.w_kd2 = (const float*)d_in[18]; P.b_kd2 = (const float*)d_in[19];
  P.w_sg  = (const float*)d_in[20]; P.b_sg  = (const float*)d_in[21];
  P.w_gs  = (const float*)d_in[22]; P.b_gs  = (const float*)d_in[23];
  P.w_glat= (const float*)d_in[24]; P.b_glat= (const float*)d_in[25];
  P.w_slat= (const float*)d_in[26]; P.b_slat= (const float*)d_in[27];
  P.w_d1gpi  = (const float*)d_in[28]; P.b_d1gpi  = (const float*)d_in[29];
  P.w_stngpi = (const float*)d_in[30]; P.b_stngpi = (const float*)d_in[31];
  P.w_ih = (const float*)d_in[32]; P.b_ih = (const float*)d_in[33];
  P.w_hh = (const float*)d_in[34]; P.b_hh = (const float*)d_in[35];
  P.out  = (float*)d_out;
  bg_main<<<NBLK, NTHR, 0, stream>>>(P);
}